// Round 4
// baseline (838.712 us; speedup 1.0000x reference)
//
// Round 7: attack the invisible per-layer stack (top-5 = logits only, so
// everything else is <78us but sums to ~174us/layer):
//  (1) scan1/scan2: bulk LDS-prefetch of the chunk's xc slice (32x256 f,
//      coalesced float4) -- removes ~900cyc cross-XCD L2-miss latency from
//      each of 32 serial timesteps; Alog loaded as float4; z issued early.
//  (2) xpconv: 2 tokens/block -> Wx L2 traffic halved (207->103 MB).
//  (3) k_redK fused into next rmsnorm (same add order) -> 4 fewer launches,
//      one x round-trip less per layer.
// GEMM unchanged from round 6 (3-buffer depth-2, swizzled, conflicts=0).
#include <hip/hip_runtime.h>

#define D_MODEL 768
#define D_INNER 1536
#define D_XZ    3072
#define D_STATE 16
#define LSEQ    1024
#define NCHUNK  32
#define CLEN    32

typedef float  floatx4 __attribute__((ext_vector_type(4)));
typedef __bf16 bf16x2  __attribute__((ext_vector_type(2)));
typedef __bf16 bf16x8  __attribute__((ext_vector_type(8)));

__device__ __forceinline__ float softplus_f(float x) {
  float e = __expf(-fabsf(x));
  return fmaxf(x, 0.f) + __logf(1.f + e);
}
__device__ __forceinline__ float silu_f(float x) {
  return x / (1.f + __expf(-x));
}
__device__ __forceinline__ void gload_lds16(const void* g, void* l) {
  __builtin_amdgcn_global_load_lds(
      (const __attribute__((address_space(1))) void*)g,
      (__attribute__((address_space(3))) void*)l, 16, 0, 0);
}

template <int N> __device__ __forceinline__ void waitcnt_vm() {
  asm volatile("s_waitcnt vmcnt(%0)" ::"n"(N) : "memory");
}
__device__ __forceinline__ void cfence() { asm volatile("" ::: "memory"); }

// ---------------- fp32 -> bf16 bulk convert (8 elems/thread) ----------------
__global__ __launch_bounds__(256) void k_cvt(const float* __restrict__ src,
                                             __bf16* __restrict__ dst) {
  size_t i = ((size_t)blockIdx.x * 256 + threadIdx.x) * 8;
  float4 a = *(const float4*)(src + i);
  float4 b = *(const float4*)(src + i + 4);
  bf16x8 o;
  o[0] = (__bf16)a.x; o[1] = (__bf16)a.y; o[2] = (__bf16)a.z; o[3] = (__bf16)a.w;
  o[4] = (__bf16)b.x; o[5] = (__bf16)b.y; o[6] = (__bf16)b.z; o[7] = (__bf16)b.w;
  *(bf16x8*)(dst + i) = o;
}

// ---------------- embed gather ----------------
__global__ __launch_bounds__(256) void k_gather(const float* __restrict__ embed,
                                                const int* __restrict__ idx,
                                                float* __restrict__ x) {
  int t = blockIdx.x;
  int tok = idx[t];
  const float* src = embed + (size_t)tok * D_MODEL;
  float* dst = x + (size_t)t * D_MODEL;
  for (int c = threadIdx.x; c < D_MODEL; c += 256) dst[c] = src[c];
}

// ---------------- rmsnorm (+optional split-K partial add & writeback) ----------------
// p != null: x_row += p0+p1+p2+p3 (same order as old k_redK), write back to xw,
// then normalize into o. p layout: 4 consecutive M*N fp32 slices.
__global__ __launch_bounds__(256) void k_rmsnorm_bf(const float* __restrict__ x,
                                                    const float* __restrict__ p,
                                                    float* __restrict__ xw,
                                                    const float* __restrict__ w,
                                                    __bf16* __restrict__ o) {
  int lane = threadIdx.x & 63;
  int row = blockIdx.x * 4 + (threadIdx.x >> 6);
  const float* xr = x + (size_t)row * D_MODEL;
  float2 v[6];
  float ss = 0.f;
#pragma unroll
  for (int i = 0; i < 6; i++) {
    int off = lane * 2 + i * 128;
    v[i] = *(const float2*)(xr + off);
    if (p) {
      size_t e = (size_t)row * D_MODEL + off;
      float2 p0 = *(const float2*)(p + e);
      float2 p1 = *(const float2*)(p + 786432 + e);
      float2 p2 = *(const float2*)(p + 2 * 786432 + e);
      float2 p3 = *(const float2*)(p + 3 * 786432 + e);
      v[i].x += ((p0.x + p1.x) + p2.x) + p3.x;
      v[i].y += ((p0.y + p1.y) + p2.y) + p3.y;
    }
    ss += v[i].x * v[i].x + v[i].y * v[i].y;
  }
#pragma unroll
  for (int m = 32; m; m >>= 1) ss += __shfl_xor(ss, m, 64);
  float r = rsqrtf(ss * (1.f / 768.f) + 1e-5f);
  __bf16* orow = o + (size_t)row * D_MODEL;
#pragma unroll
  for (int i = 0; i < 6; i++) {
    int off = lane * 2 + i * 128;
    if (p) *(float2*)(xw + (size_t)row * D_MODEL + off) = v[i];
    float2 wv = *(const float2*)(w + off);
    bf16x2 pk;
    pk[0] = (__bf16)(v[i].x * r * wv.x);
    pk[1] = (__bf16)(v[i].y * r * wv.y);
    *(bf16x2*)(orow + off) = pk;
  }
}

// ---------------- bf16 NT GEMM: 3-buffer depth-2 pipeline, swizzled ----------------
template <int TM, int TN, int SK>
__global__ __launch_bounds__(256, 3) void k_gemm_bb(const __bf16* __restrict__ A,
                                                    const __bf16* __restrict__ B,
                                                    const float* res, float* __restrict__ C,
                                                    int M, int N, int K, int mTiles) {
  constexpr int MT  = TM / 32;
  constexpr int NTL = TN / 32;
  constexpr int NLA = TM / 64;
  constexpr int NLB = TN / 64;
  constexpr int NL  = NLA + NLB;
  __shared__ __attribute__((aligned(16))) __bf16 As[3][TM * 32];
  __shared__ __attribute__((aligned(16))) __bf16 Bs[3][TN * 32];
  const int tid = threadIdx.x;
  const int lane = tid & 63, wave = tid >> 6;
  const int fr = lane & 15, q = lane >> 4;

  int id = blockIdx.x;
  int per = gridDim.x >> 3;
  int v = (id & 7) * per + (id >> 3);             // XCD-contiguous mapping
  int s = 0, rr = v;
  if (SK > 1) { int perS = gridDim.x / SK; s = v / perS; rr = v % perS; }
  int nt = rr / mTiles, mt_ = rr % mTiles;
  const int Mblk = mt_ * TM, Nblk = nt * TN;
  const int wm = (wave & 1) * (TM / 2), wn = (wave >> 1) * (TN / 2);
  const int Ks = K / SK;

  const int row_s = tid >> 2;
  const int cs = ((tid & 3) ^ ((row_s >> 1) & 3)) * 8;  // swizzled source chunk
  const __bf16* Ag = A + (size_t)(Mblk + row_s) * K + (size_t)s * Ks + cs;
  const __bf16* Bg = B + (size_t)(Nblk + row_s) * K + (size_t)s * Ks + cs;
  if (SK > 1) C += (size_t)s * M * N;

  floatx4 acc[MT][NTL];
#pragma unroll
  for (int i = 0; i < MT; i++)
#pragma unroll
    for (int j = 0; j < NTL; j++) {
      floatx4 z = {0.f, 0.f, 0.f, 0.f};
      acc[i][j] = z;
    }

  const int KT = Ks >> 5;

#define STAGE_T(t, b)                                                         \
  do {                                                                        \
    const int _k0 = (t) << 5;                                                 \
    _Pragma("unroll") for (int i = 0; i < NLA; i++)                           \
        gload_lds16(Ag + (size_t)(64 * i) * K + _k0,                          \
                    &As[b][tid * 8 + i * 2048]);                              \
    _Pragma("unroll") for (int i = 0; i < NLB; i++)                           \
        gload_lds16(Bg + (size_t)(64 * i) * K + _k0,                          \
                    &Bs[b][tid * 8 + i * 2048]);                              \
  } while (0)

#define STEP_T(b, WN)                                                         \
  do {                                                                        \
    waitcnt_vm<WN>();                                                         \
    __builtin_amdgcn_s_barrier();                                             \
    cfence();                                                                 \
    bf16x8 af[MT], bfr[NTL];                                                  \
    _Pragma("unroll") for (int mt = 0; mt < MT; mt++) {                       \
      const int R = wm + mt * 16 + fr;                                        \
      af[mt] = *(const bf16x8*)&As[b][R * 32 + ((q ^ ((R >> 1) & 3)) << 3)];  \
    }                                                                         \
    _Pragma("unroll") for (int ntl = 0; ntl < NTL; ntl++) {                   \
      const int R = wn + ntl * 16 + fr;                                       \
      bfr[ntl] = *(const bf16x8*)&Bs[b][R * 32 + ((q ^ ((R >> 1) & 3)) << 3)]; \
    }                                                                         \
    _Pragma("unroll") for (int mt = 0; mt < MT; mt++)                         \
      _Pragma("unroll") for (int ntl = 0; ntl < NTL; ntl++)                   \
        acc[mt][ntl] = __builtin_amdgcn_mfma_f32_16x16x32_bf16(               \
            af[mt], bfr[ntl], acc[mt][ntl], 0, 0, 0);                         \
    cfence();                                                                 \
    __builtin_amdgcn_s_barrier();                                             \
    cfence();                                                                 \
  } while (0)

  STAGE_T(0, 0);
  STAGE_T(1, 1);

  int bcur = 0, bpre = 2;
  for (int kt = 0; kt < KT - 2; ++kt) {
    STAGE_T(kt + 2, bpre);
    STEP_T(bcur, 2 * NL);
    bcur = (bcur == 2) ? 0 : bcur + 1;
    bpre = (bpre == 2) ? 0 : bpre + 1;
  }
  STEP_T(bcur, NL);
  bcur = (bcur == 2) ? 0 : bcur + 1;
  STEP_T(bcur, 0);

#undef STAGE_T
#undef STEP_T

#pragma unroll
  for (int mt = 0; mt < MT; mt++)
#pragma unroll
    for (int ntl = 0; ntl < NTL; ntl++) {
      int r = Mblk + wm + mt * 16 + q * 4;
      int c = Nblk + wn + ntl * 16 + fr;
#pragma unroll
      for (int i = 0; i < 4; i++) {
        size_t o = (size_t)(r + i) * N + c;
        float vv = acc[mt][ntl][i];
        if (res) vv += res[o];
        C[o] = vv;
      }
    }
}

// ---------------- fused conv(k=4)+bias+silu -> xc, xp = xc @ Wx^T ----------------
// 2 tokens per block: Wx L2 traffic halved. Same per-token FP order.
__global__ __launch_bounds__(256, 2) void k_xpconv(const float* __restrict__ xz,
                                                   const float* __restrict__ cw4,
                                                   const float* __restrict__ cb,
                                                   const float* __restrict__ Wx,
                                                   float* __restrict__ xc,
                                                   float* __restrict__ xp) {
  __shared__ float red[2][4][33];
  int t0 = blockIdx.x * 2;
  int wave = threadIdx.x >> 6, lane = threadIdx.x & 63;
  float acc0[33], acc1[33];
#pragma unroll
  for (int j = 0; j < 33; j++) { acc0[j] = 0.f; acc1[j] = 0.f; }
  for (int ii = 0; ii < 6; ii++) {
    int k = wave * 384 + ii * 64 + lane;
    float4 w = *(const float4*)(cw4 + (size_t)k * 4);
    float wv[4] = {w.x, w.y, w.z, w.w};
    float cbk = cb[k];
    float vv0 = cbk, vv1 = cbk;
#pragma unroll
    for (int jj = 0; jj < 4; jj++) {
      int ts = t0 - 3 + jj;  // block-uniform branch
      if (ts >= 0) vv0 += wv[jj] * xz[(size_t)ts * D_XZ + k];
    }
#pragma unroll
    for (int jj = 0; jj < 4; jj++) {
      int ts = t0 - 2 + jj;  // token t0+1 window (t0+1 >= 1, only jj=0 can be <0... guard anyway)
      if (ts >= 0) vv1 += wv[jj] * xz[(size_t)ts * D_XZ + k];
    }
    float xc0 = silu_f(vv0);
    float xc1 = silu_f(vv1);
    xc[(size_t)t0 * D_INNER + k] = xc0;
    xc[(size_t)(t0 + 1) * D_INNER + k] = xc1;
#pragma unroll
    for (int j = 0; j < 33; j++) {
      float wx = Wx[(size_t)j * D_INNER + k];
      acc0[j] += xc0 * wx;
      acc1[j] += xc1 * wx;
    }
  }
#pragma unroll
  for (int j = 0; j < 33; j++) {
    float s0 = acc0[j], s1 = acc1[j];
#pragma unroll
    for (int m = 32; m; m >>= 1) {
      s0 += __shfl_xor(s0, m, 64);
      s1 += __shfl_xor(s1, m, 64);
    }
    if (lane == j) { red[0][wave][j] = s0; red[1][wave][j] = s1; }
  }
  __syncthreads();
  int wv2 = threadIdx.x >> 6, jl = threadIdx.x & 63;
  if (wv2 < 2 && jl < 33)
    xp[(size_t)(t0 + wv2) * 33 + jl] =
        red[wv2][0][jl] + red[wv2][1][jl] + red[wv2][2][jl] + red[wv2][3][jl];
}

// ---------------- scan phase 1 (xc slice prefetched to LDS) ----------------
__global__ __launch_bounds__(256) void k_scan1(const float* __restrict__ xp,
                                               const float* __restrict__ xc,
                                               const float* __restrict__ dtw,
                                               const float* __restrict__ dtb,
                                               const float* __restrict__ Alog,
                                               float* __restrict__ hend,
                                               float* __restrict__ Pp) {
  __shared__ float sxp[CLEN * 33];
  __shared__ float sxc[CLEN * 256];
  int c = blockIdx.x;
  int dblk = blockIdx.y * 256;
  int d = dblk + threadIdx.x;
  for (int i = threadIdx.x; i < CLEN * 33; i += 256) sxp[i] = xp[(size_t)c * CLEN * 33 + i];
  {
    const float* src = xc + (size_t)(c * CLEN) * D_INNER + dblk;
    for (int i = threadIdx.x; i < CLEN * 64; i += 256) {
      int row = i >> 6, c4 = i & 63;
      *(float4*)&sxc[row * 256 + c4 * 4] = *(const float4*)(src + (size_t)row * D_INNER + c4 * 4);
    }
  }
  __syncthreads();
  float Av[16];
  {
    const float4* Ar = (const float4*)(Alog + (size_t)d * 16);
    float4 a0 = Ar[0], a1 = Ar[1], a2 = Ar[2], a3 = Ar[3];
    Av[0] = -__expf(a0.x); Av[1] = -__expf(a0.y); Av[2] = -__expf(a0.z); Av[3] = -__expf(a0.w);
    Av[4] = -__expf(a1.x); Av[5] = -__expf(a1.y); Av[6] = -__expf(a1.z); Av[7] = -__expf(a1.w);
    Av[8] = -__expf(a2.x); Av[9] = -__expf(a2.y); Av[10] = -__expf(a2.z); Av[11] = -__expf(a2.w);
    Av[12] = -__expf(a3.x); Av[13] = -__expf(a3.y); Av[14] = -__expf(a3.z); Av[15] = -__expf(a3.w);
  }
  float w_ = dtw[d], b_ = dtb[d];
  float h[16], P[16];
#pragma unroll
  for (int n = 0; n < 16; n++) { h[n] = 0.f; P[n] = 1.f; }
  for (int tl = 0; tl < CLEN; tl++) {
    float dtr = sxp[tl * 33];
    float xv = sxc[tl * 256 + threadIdx.x];
    float dt = softplus_f(dtr * w_ + b_);
    float sx = dt * xv;
#pragma unroll
    for (int n = 0; n < 16; n++) {
      float dA = __expf(dt * Av[n]);
      h[n] = dA * h[n] + sx * sxp[tl * 33 + 1 + n];
      P[n] *= dA;
    }
  }
  size_t o = ((size_t)c * D_INNER + d) * 16;
#pragma unroll
  for (int n = 0; n < 16; n++) { hend[o + n] = h[n]; Pp[o + n] = P[n]; }
}

// ---------------- scan phase 2: inline chunk-prefix + rescan (xc in LDS) ----------------
__global__ __launch_bounds__(256) void k_scan2(const float* __restrict__ xp,
                                               const float* __restrict__ xc,
                                               const float* __restrict__ xz,
                                               const float* __restrict__ dtw,
                                               const float* __restrict__ dtb,
                                               const float* __restrict__ Alog,
                                               const float* __restrict__ Dp,
                                               const float* __restrict__ hend,
                                               const float* __restrict__ Pp,
                                               __bf16* __restrict__ g) {
  __shared__ float sxp[CLEN * 33];
  __shared__ float sxc[CLEN * 256];
  int c = blockIdx.x;
  int dblk = blockIdx.y * 256;
  int d = dblk + threadIdx.x;
  for (int i = threadIdx.x; i < CLEN * 33; i += 256) sxp[i] = xp[(size_t)c * CLEN * 33 + i];
  {
    const float* src = xc + (size_t)(c * CLEN) * D_INNER + dblk;
    for (int i = threadIdx.x; i < CLEN * 64; i += 256) {
      int row = i >> 6, c4 = i & 63;
      *(float4*)&sxc[row * 256 + c4 * 4] = *(const float4*)(src + (size_t)row * D_INNER + c4 * 4);
    }
  }
  __syncthreads();
  float Av[16];
  {
    const float4* Ar = (const float4*)(Alog + (size_t)d * 16);
    float4 a0 = Ar[0], a1 = Ar[1], a2 = Ar[2], a3 = Ar[3];
    Av[0] = -__expf(a0.x); Av[1] = -__expf(a0.y); Av[2] = -__expf(a0.z); Av[3] = -__expf(a0.w);
    Av[4] = -__expf(a1.x); Av[5] = -__expf(a1.y); Av[6] = -__expf(a1.z); Av[7] = -__expf(a1.w);
    Av[8] = -__expf(a2.x); Av[9] = -__expf(a2.y); Av[10] = -__expf(a2.z); Av[11] = -__expf(a2.w);
    Av[12] = -__expf(a3.x); Av[13] = -__expf(a3.y); Av[14] = -__expf(a3.z); Av[15] = -__expf(a3.w);
  }
  float w_ = dtw[d], b_ = dtb[d], Dv = Dp[d];
  float h[16];
#pragma unroll
  for (int n = 0; n < 16; n++) h[n] = 0.f;
  for (int c2 = 0; c2 < c; c2++) {
    size_t o = ((size_t)c2 * D_INNER + d) * 16;
#pragma unroll
    for (int n4 = 0; n4 < 4; n4++) {
      float4 hv = *(const float4*)(hend + o + n4 * 4);
      float4 pv = *(const float4*)(Pp + o + n4 * 4);
      h[n4 * 4 + 0] = pv.x * h[n4 * 4 + 0] + hv.x;
      h[n4 * 4 + 1] = pv.y * h[n4 * 4 + 1] + hv.y;
      h[n4 * 4 + 2] = pv.z * h[n4 * 4 + 2] + hv.z;
      h[n4 * 4 + 3] = pv.w * h[n4 * 4 + 3] + hv.w;
    }
  }
  for (int tl = 0; tl < CLEN; tl++) {
    int t = c * CLEN + tl;
    float z = xz[(size_t)t * D_XZ + D_INNER + d];  // issued early, consumed last
    float dtr = sxp[tl * 33];
    float xv = sxc[tl * 256 + threadIdx.x];
    float dt = softplus_f(dtr * w_ + b_);
    float sx = dt * xv;
    float y = 0.f;
#pragma unroll
    for (int n = 0; n < 16; n++) {
      float dA = __expf(dt * Av[n]);
      h[n] = dA * h[n] + sx * sxp[tl * 33 + 1 + n];
      y += h[n] * sxp[tl * 33 + 17 + n];
    }
    g[(size_t)t * D_INNER + d] = (__bf16)((y + xv * Dv) * silu_f(z));
  }
}

extern "C" void kernel_launch(void* const* d_in, const int* in_sizes, int n_in,
                              void* d_out, int out_size, void* d_ws, size_t ws_size,
                              hipStream_t stream) {
  const int*   idx     = (const int*)d_in[0];
  const float* embed   = (const float*)d_in[1];
  const float* norm_w  = (const float*)d_in[2];
  const float* W_in    = (const float*)d_in[3];
  const float* conv_w  = (const float*)d_in[4];
  const float* conv_b  = (const float*)d_in[5];
  const float* W_x     = (const float*)d_in[6];
  const float* dt_w    = (const float*)d_in[7];
  const float* dt_b    = (const float*)d_in[8];
  const float* A_log   = (const float*)d_in[9];
  const float* Dp      = (const float*)d_in[10];
  const float* out_w   = (const float*)d_in[11];
  const float* norm_fw = (const float*)d_in[12];
  float* out = (float*)d_out;

  // ---- workspace layout (pool region re-used for bf16 embed at the end) ----
  float*  x    = (float*)d_ws;                     // 786432 f
  __bf16* xnb  = (__bf16*)(x + 786432);            // 786432 bf
  float*  xp   = (float*)(xnb + 786432);           // 33792 f
  float*  Pp   = xp + 33792;                       // 786432 f
  __bf16* gbf  = (__bf16*)(Pp + 786432);           // 1572864 bf
  __bf16* pool = gbf + 1572864;                    // pool: ~50.3 MB
  __bf16* W_in_bf  = pool;                         // 9437184 bf
  __bf16* out_w_bf = pool + 9437184;               // 4718592 bf
  float*  xz   = (float*)(out_w_bf + 4718592);     // 3145728 f (also split-K partials)
  float*  xc   = xz + 3145728;                     // 1572864 f
  float*  hend = xc + 1572864;                     // 786432 f
  __bf16* emb_bf = pool;                           // 24576000 bf (aliases pool AFTER layers)

  k_cvt<<<4608, 256, 0, stream>>>(W_in, W_in_bf);      // 9,437,184 elems
  k_cvt<<<2304, 256, 0, stream>>>(out_w, out_w_bf);    // 4,718,592 elems

  k_gather<<<1024, 256, 0, stream>>>(embed, idx, x);

  for (int l = 0; l < 4; l++) {
    // l==0: plain norm; l>0: fold previous layer's split-K partials into x first
    k_rmsnorm_bf<<<256, 256, 0, stream>>>(x, l ? xz : nullptr, x,
                                          norm_w + (size_t)l * D_MODEL, xnb);
    // xz = xn @ W_in^T : M=1024 N=3072 K=768 -> <64,64>: 48 nt x 16 mt = 768 blocks
    k_gemm_bb<64, 64, 1><<<768, 256, 0, stream>>>(xnb, W_in_bf + (size_t)l * D_XZ * D_MODEL,
                                                  nullptr, xz, 1024, D_XZ, D_MODEL, 16);
    k_xpconv<<<512, 256, 0, stream>>>(xz, conv_w + (size_t)l * D_INNER * 4,
                                      conv_b + (size_t)l * D_INNER,
                                      W_x + (size_t)l * 33 * D_INNER, xc, xp);
    k_scan1<<<dim3(NCHUNK, 6), 256, 0, stream>>>(xp, xc, dt_w + (size_t)l * D_INNER,
                                                 dt_b + (size_t)l * D_INNER,
                                                 A_log + (size_t)l * D_INNER * 16, hend, Pp);
    k_scan2<<<dim3(NCHUNK, 6), 256, 0, stream>>>(xp, xc, xz, dt_w + (size_t)l * D_INNER,
                                                 dt_b + (size_t)l * D_INNER,
                                                 A_log + (size_t)l * D_INNER * 16,
                                                 Dp + (size_t)l * D_INNER, hend, Pp, gbf);
    // out-proj split-K=4: partials into xz (dead after scan2); folded by next rmsnorm
    k_gemm_bb<64, 64, 4><<<768, 256, 0, stream>>>(gbf, out_w_bf + (size_t)l * D_MODEL * D_INNER,
                                                  nullptr, xz, 1024, D_MODEL, D_INNER, 16);
  }

  // final norm folds layer-3 partials (read xz BEFORE emb_bf cvt overwrites pool)
  k_rmsnorm_bf<<<256, 256, 0, stream>>>(x, xz, x, norm_fw, xnb);
  k_cvt<<<12000, 256, 0, stream>>>(embed, emb_bf);     // 24,576,000 elems
  // logits = xn @ embed^T : M=1024 N=32000 K=768 -> 250 nt x 8 mt = 2000 blocks
  k_gemm_bb<128, 128, 1><<<2000, 256, 0, stream>>>(xnb, emb_bf, nullptr, out,
                                                   1024, 32000, D_MODEL, 8);
}